// Round 1
// baseline (2548.326 us; speedup 1.0000x reference)
//
#include <hip/hip_runtime.h>
#include <hip/hip_bf16.h>

#define N_NODES 203769
#define N_EDGES 234355
#define F_IN    165
#define F_HID   128
#define F_OUT   64
#define BN_EPS  1e-5f

// ---------------------------------------------------------------------------
// degree / dinv
// ---------------------------------------------------------------------------
__global__ void k_deg_init(float* deg) {
    int i = blockIdx.x * 256 + threadIdx.x;
    if (i < N_NODES) deg[i] = 1.0f;  // self-loop contributes 1
}

__global__ void k_deg_count(const int* dst, float* deg) {
    int e = blockIdx.x * 256 + threadIdx.x;
    if (e < N_EDGES) atomicAdd(&deg[dst[e]], 1.0f);
}

__global__ void k_deg_rsqrt(float* deg) {
    int i = blockIdx.x * 256 + threadIdx.x;
    if (i < N_NODES) deg[i] = rsqrtf(deg[i]);  // deg >= 1 always
}

// ---------------------------------------------------------------------------
// GEMM1: h1[N,128] = x[N,165] @ W1[165,128]   (fp32 vector ALU)
// 32-row tile in LDS (stride padded to 168 for 16B-aligned float4 reads).
// 256 threads: colpair cp = t&63 -> cols {cp, cp+64}; rowgroup rg = t>>6 -> 8 rows.
// ---------------------------------------------------------------------------
__global__ __launch_bounds__(256) void k_gemm1(const float* __restrict__ x,
                                               const float* __restrict__ W1,
                                               float* __restrict__ h1) {
    __shared__ float xs[32 * 168];
    const int row0 = blockIdx.x * 32;
    const int t = threadIdx.x;

    {
        const float* src = x + (size_t)row0 * F_IN;
        const int maxe = (N_NODES - row0) * F_IN;
        for (int fi = t; fi < 32 * F_IN; fi += 256) {
            int r = fi / F_IN;
            int k = fi - r * F_IN;
            xs[r * 168 + k] = (fi < maxe) ? src[fi] : 0.0f;
        }
        for (int r = t; r < 32; r += 256) {
            xs[r * 168 + 165] = 0.0f;
            xs[r * 168 + 166] = 0.0f;
            xs[r * 168 + 167] = 0.0f;
        }
    }
    __syncthreads();

    const int cp = t & 63;
    const int rg = t >> 6;  // 0..3, rows rg*8 .. rg*8+7

    float acc0[8], acc1[8];
#pragma unroll
    for (int r = 0; r < 8; r++) { acc0[r] = 0.0f; acc1[r] = 0.0f; }

    for (int k4 = 0; k4 < 164; k4 += 4) {
        float4 xv[8];
#pragma unroll
        for (int r = 0; r < 8; r++)
            xv[r] = *(const float4*)&xs[(rg * 8 + r) * 168 + k4];
        float w0[4], w1v[4];
#pragma unroll
        for (int j = 0; j < 4; j++) {
            w0[j]  = W1[(k4 + j) * F_HID + cp];
            w1v[j] = W1[(k4 + j) * F_HID + cp + 64];
        }
#pragma unroll
        for (int r = 0; r < 8; r++) {
            acc0[r] = fmaf(xv[r].x, w0[0], acc0[r]);
            acc0[r] = fmaf(xv[r].y, w0[1], acc0[r]);
            acc0[r] = fmaf(xv[r].z, w0[2], acc0[r]);
            acc0[r] = fmaf(xv[r].w, w0[3], acc0[r]);
            acc1[r] = fmaf(xv[r].x, w1v[0], acc1[r]);
            acc1[r] = fmaf(xv[r].y, w1v[1], acc1[r]);
            acc1[r] = fmaf(xv[r].z, w1v[2], acc1[r]);
            acc1[r] = fmaf(xv[r].w, w1v[3], acc1[r]);
        }
    }
    {   // remainder k = 164
        float w0  = W1[164 * F_HID + cp];
        float w1r = W1[164 * F_HID + cp + 64];
#pragma unroll
        for (int r = 0; r < 8; r++) {
            float xvr = xs[(rg * 8 + r) * 168 + 164];
            acc0[r] = fmaf(xvr, w0, acc0[r]);
            acc1[r] = fmaf(xvr, w1r, acc1[r]);
        }
    }
#pragma unroll
    for (int r = 0; r < 8; r++) {
        int row = row0 + rg * 8 + r;
        if (row < N_NODES) {
            h1[(size_t)row * F_HID + cp]      = acc0[r];
            h1[(size_t)row * F_HID + cp + 64] = acc1[r];
        }
    }
}

// ---------------------------------------------------------------------------
// conv self-loop: out[i,:] = h[i,:] * dinv[i]^2   (plain write — runs first)
// ---------------------------------------------------------------------------
template <int C>
__global__ void k_conv_self(const float* __restrict__ h,
                            const float* __restrict__ dinv,
                            float* __restrict__ out) {
    int tid = blockIdx.x * 256 + threadIdx.x;  // over N*C/4 float4s
    if (tid >= N_NODES * (C / 4)) return;
    int row = tid / (C / 4);
    float di = dinv[row];
    float s = di * di;
    float4 v = ((const float4*)h)[tid];
    v.x *= s; v.y *= s; v.z *= s; v.w *= s;
    ((float4*)out)[tid] = v;
}

// ---------------------------------------------------------------------------
// conv edge: out[d,:] += h[s,:] * dinv[s]*dinv[d]   (atomic scatter)
// TPE = C/4 threads per edge, each handles one float4.
// ---------------------------------------------------------------------------
template <int C, int TPE>
__global__ void k_conv_edge(const float* __restrict__ h,
                            const int* __restrict__ src,
                            const int* __restrict__ dst,
                            const float* __restrict__ dinv,
                            float* __restrict__ out) {
    int tid = blockIdx.x * 256 + threadIdx.x;
    int e = tid / TPE;
    if (e >= N_EDGES) return;
    int q = tid & (TPE - 1);
    int s = src[e], d = dst[e];
    float nrm = dinv[s] * dinv[d];
    float4 v = *(const float4*)&h[(size_t)s * C + q * 4];
    float* o = &out[(size_t)d * C + q * 4];
    atomicAdd(o + 0, v.x * nrm);
    atomicAdd(o + 1, v.y * nrm);
    atomicAdd(o + 2, v.z * nrm);
    atomicAdd(o + 3, v.w * nrm);
}

// ---------------------------------------------------------------------------
// BN stats: per-column sum and sum-of-squares (atomics into zeroed buffers)
// ---------------------------------------------------------------------------
template <int C>
__global__ __launch_bounds__(256) void k_bn_stats(const float* __restrict__ src,
                                                  float* __restrict__ gsum,
                                                  float* __restrict__ gsumsq) {
    const int RG = 256 / C;
    int t = threadIdx.x;
    int col = t & (C - 1);
    int rg = t / C;
    float s = 0.0f, s2 = 0.0f;
    int stride = gridDim.x * RG;
    for (int r = blockIdx.x * RG + rg; r < N_NODES; r += stride) {
        float v = src[(size_t)r * C + col];
        s += v;
        s2 = fmaf(v, v, s2);
    }
    __shared__ float sm[256], sq[256];
    sm[t] = s; sq[t] = s2;
    __syncthreads();
    if (t < C) {
#pragma unroll
        for (int i = 1; i < RG; i++) {
            s  += sm[t + i * C];
            s2 += sq[t + i * C];
        }
        atomicAdd(&gsum[col], s);
        atomicAdd(&gsumsq[col], s2);
    }
}

// scale = g*rstd ; shift = be - mean*scale
__global__ void k_bn_finalize(const float* gsum, const float* gsumsq,
                              const float* g, const float* be,
                              float* sc, float* sh, int C) {
    int c = threadIdx.x;
    if (c < C) {
        const float invn = 1.0f / (float)N_NODES;
        float mean = gsum[c] * invn;
        float var = gsumsq[c] * invn - mean * mean;
        float rstd = rsqrtf(var + BN_EPS);
        float scale = g[c] * rstd;
        sc[c] = scale;
        sh[c] = fmaf(-mean, scale, be[c]);
    }
}

// ---------------------------------------------------------------------------
// GEMM2 fused with BN1-apply + ReLU on load:
// h2[N,64] = relu(bn1(out1[N,128])) @ W2[128,64]
// 32-row tile; 256 threads: cp = t&31 -> cols {cp, cp+32}; rg = t>>5 -> 4 rows.
// ---------------------------------------------------------------------------
__global__ __launch_bounds__(256) void k_gemm2(const float* __restrict__ out1,
                                               const float* __restrict__ sc1,
                                               const float* __restrict__ sh1,
                                               const float* __restrict__ W2,
                                               float* __restrict__ h2) {
    __shared__ float xs[32 * 128];
    const int row0 = blockIdx.x * 32;
    const int t = threadIdx.x;
    {
        const float* src = out1 + (size_t)row0 * F_HID;
        const int maxe = (N_NODES - row0) * F_HID;
        for (int fi = t; fi < 32 * F_HID; fi += 256) {
            int c = fi & 127;
            float v = (fi < maxe) ? src[fi] : 0.0f;
            v = fmaf(v, sc1[c], sh1[c]);
            xs[fi] = fmaxf(v, 0.0f);
        }
    }
    __syncthreads();

    const int cp = t & 31;
    const int rg = t >> 5;  // 0..7, rows rg*4 .. +3

    float acc0[4], acc1[4];
#pragma unroll
    for (int r = 0; r < 4; r++) { acc0[r] = 0.0f; acc1[r] = 0.0f; }

    for (int k4 = 0; k4 < F_HID; k4 += 4) {
        float4 xv[4];
#pragma unroll
        for (int r = 0; r < 4; r++)
            xv[r] = *(const float4*)&xs[(rg * 4 + r) * 128 + k4];
        float w0[4], w1v[4];
#pragma unroll
        for (int j = 0; j < 4; j++) {
            w0[j]  = W2[(k4 + j) * F_OUT + cp];
            w1v[j] = W2[(k4 + j) * F_OUT + cp + 32];
        }
#pragma unroll
        for (int r = 0; r < 4; r++) {
            acc0[r] = fmaf(xv[r].x, w0[0], acc0[r]);
            acc0[r] = fmaf(xv[r].y, w0[1], acc0[r]);
            acc0[r] = fmaf(xv[r].z, w0[2], acc0[r]);
            acc0[r] = fmaf(xv[r].w, w0[3], acc0[r]);
            acc1[r] = fmaf(xv[r].x, w1v[0], acc1[r]);
            acc1[r] = fmaf(xv[r].y, w1v[1], acc1[r]);
            acc1[r] = fmaf(xv[r].z, w1v[2], acc1[r]);
            acc1[r] = fmaf(xv[r].w, w1v[3], acc1[r]);
        }
    }
#pragma unroll
    for (int r = 0; r < 4; r++) {
        int row = row0 + rg * 4 + r;
        if (row < N_NODES) {
            h2[(size_t)row * F_OUT + cp]      = acc0[r];
            h2[(size_t)row * F_OUT + cp + 32] = acc1[r];
        }
    }
}

// ---------------------------------------------------------------------------
// Final: per row r:
//   hf = bn2(out2[r,:])             -> d_out[r*64 + c]          (no relu)
//   a  = relu(hf @ Wp1 + bp1)
//   z  = a @ Wp2 + bp2              -> d_out[N*64 + r*64 + c]
// One wave per row; 64x64 dots via lane shuffles; Wp1/Wp2 staged in LDS.
// ---------------------------------------------------------------------------
__global__ __launch_bounds__(256) void k_final(const float* __restrict__ out2,
                                               const float* __restrict__ sc2,
                                               const float* __restrict__ sh2,
                                               const float* __restrict__ Wp1,
                                               const float* __restrict__ bp1,
                                               const float* __restrict__ Wp2,
                                               const float* __restrict__ bp2,
                                               float* __restrict__ out) {
    __shared__ float w1s[64 * 64];
    __shared__ float w2s[64 * 64];
    for (int i = threadIdx.x; i < 64 * 64; i += 256) {
        w1s[i] = Wp1[i];
        w2s[i] = Wp2[i];
    }
    __syncthreads();

    const int lane = threadIdx.x & 63;
    const int wid = threadIdx.x >> 6;
    const float scale = sc2[lane];
    const float shift = sh2[lane];
    const float b1v = bp1[lane];
    const float b2v = bp2[lane];
    const int nwaves = gridDim.x * 4;

    for (int row = blockIdx.x * 4 + wid; row < N_NODES; row += nwaves) {
        float hv = fmaf(out2[(size_t)row * 64 + lane], scale, shift);
        out[(size_t)row * 64 + lane] = hv;

        float acc = b1v;
#pragma unroll
        for (int k = 0; k < 64; k++) {
            float hk = __shfl(hv, k, 64);
            acc = fmaf(hk, w1s[k * 64 + lane], acc);
        }
        float a = fmaxf(acc, 0.0f);

        float acc2 = b2v;
#pragma unroll
        for (int k = 0; k < 64; k++) {
            float ak = __shfl(a, k, 64);
            acc2 = fmaf(ak, w2s[k * 64 + lane], acc2);
        }
        out[(size_t)(N_NODES) * 64 + (size_t)row * 64 + lane] = acc2;
    }
}

// ---------------------------------------------------------------------------
// launch
// ---------------------------------------------------------------------------
extern "C" void kernel_launch(void* const* d_in, const int* in_sizes, int n_in,
                              void* d_out, int out_size, void* d_ws, size_t ws_size,
                              hipStream_t stream) {
    const float* x   = (const float*)d_in[0];
    const int*   ei  = (const int*)d_in[1];
    const float* W1  = (const float*)d_in[2];
    // b1 (d_in[3]) skipped: column-constant shift is cancelled by BN1
    const float* g1  = (const float*)d_in[4];
    const float* be1 = (const float*)d_in[5];
    const float* W2  = (const float*)d_in[6];
    // b2 (d_in[7]) skipped: cancelled by BN2
    const float* g2  = (const float*)d_in[8];
    const float* be2 = (const float*)d_in[9];
    const float* Wp1 = (const float*)d_in[10];
    const float* bp1 = (const float*)d_in[11];
    const float* Wp2 = (const float*)d_in[12];
    const float* bp2 = (const float*)d_in[13];

    const int* src = ei;            // edge_index[0]
    const int* dst = ei + N_EDGES;  // edge_index[1]

    const size_t NM128 = (size_t)N_NODES * F_HID;
    float* ws = (float*)d_ws;
    float* A   = ws;                 // h1 (N*128), later h2 (N*64)
    float* B   = ws + NM128;         // out1 (N*128), later out2 (N*64)
    float* deg = ws + 2 * NM128;     // N
    float* st  = deg + N_NODES;      // stats region, 768 floats
    float* s1   = st;        // 128
    float* s1q  = st + 128;  // 128
    float* sc1  = st + 256;  // 128
    float* sh1  = st + 384;  // 128
    float* s2   = st + 512;  // 64
    float* s2q  = st + 576;  // 64
    float* sc2  = st + 640;  // 64
    float* sh2  = st + 704;  // 64

    hipMemsetAsync(st, 0, 768 * sizeof(float), stream);

    // degree -> dinv
    k_deg_init<<<(N_NODES + 255) / 256, 256, 0, stream>>>(deg);
    k_deg_count<<<(N_EDGES + 255) / 256, 256, 0, stream>>>(dst, deg);
    k_deg_rsqrt<<<(N_NODES + 255) / 256, 256, 0, stream>>>(deg);

    // layer 1
    k_gemm1<<<(N_NODES + 31) / 32, 256, 0, stream>>>(x, W1, A);
    k_conv_self<128><<<(N_NODES * 32 + 255) / 256, 256, 0, stream>>>(A, deg, B);
    k_conv_edge<128, 32><<<(N_EDGES * 32 + 255) / 256, 256, 0, stream>>>(A, src, dst, deg, B);
    k_bn_stats<128><<<1024, 256, 0, stream>>>(B, s1, s1q);
    k_bn_finalize<<<1, 128, 0, stream>>>(s1, s1q, g1, be1, sc1, sh1, 128);

    // layer 2 (BN1+relu fused into GEMM2 load)
    k_gemm2<<<(N_NODES + 31) / 32, 256, 0, stream>>>(B, sc1, sh1, W2, A);
    k_conv_self<64><<<(N_NODES * 16 + 255) / 256, 256, 0, stream>>>(A, deg, B);
    k_conv_edge<64, 16><<<(N_EDGES * 16 + 255) / 256, 256, 0, stream>>>(A, src, dst, deg, B);
    k_bn_stats<64><<<1024, 256, 0, stream>>>(B, s2, s2q);
    k_bn_finalize<<<1, 64, 0, stream>>>(s2, s2q, g2, be2, sc2, sh2, 64);

    // BN2-apply + MLP head, writes both outputs
    k_final<<<2048, 256, 0, stream>>>(B, sc2, sh2, Wp1, bp1, Wp2, bp2, (float*)d_out);
}

// Round 2
// 1126.615 us; speedup vs baseline: 2.2619x; 2.2619x over previous
//
#include <hip/hip_runtime.h>
#include <hip/hip_bf16.h>

#define N_NODES 203769
#define N_EDGES 234355
#define F_IN    165
#define F_HID   128
#define F_OUT   64
#define BN_EPS  1e-5f
#define NB_SCAN 796   // ceil(N_NODES/256)

// ---------------------------------------------------------------------------
// CSR build: count in-degree (int atomics)
// ---------------------------------------------------------------------------
__global__ void k_count(const int* __restrict__ dst, int* __restrict__ cnt) {
    int e = blockIdx.x * 256 + threadIdx.x;
    if (e < N_EDGES) atomicAdd(&cnt[dst[e]], 1);
}

// scanA: per-block (256-elem chunk) sums -> partials[b]
__global__ __launch_bounds__(256) void k_scanA(const int* __restrict__ cnt,
                                               int* __restrict__ partials) {
    __shared__ int sm[256];
    int t = threadIdx.x;
    int i = blockIdx.x * 256 + t;
    int v = (i < N_NODES) ? cnt[i] : 0;
    sm[t] = v;
    __syncthreads();
    for (int off = 128; off > 0; off >>= 1) {
        if (t < off) sm[t] += sm[t + off];
        __syncthreads();
    }
    if (t == 0) partials[blockIdx.x] = sm[0];
}

// scanB: exclusive scan of NB_SCAN partials in one 1024-thread block
__global__ __launch_bounds__(1024) void k_scanB(int* __restrict__ partials,
                                                int* __restrict__ row_ptr) {
    __shared__ int sm[1024];
    int t = threadIdx.x;
    int v = (t < NB_SCAN) ? partials[t] : 0;
    sm[t] = v;
    __syncthreads();
    for (int off = 1; off < 1024; off <<= 1) {
        int add = (t >= off) ? sm[t - off] : 0;
        __syncthreads();
        sm[t] += add;
        __syncthreads();
    }
    if (t < NB_SCAN) partials[t] = sm[t] - v;   // exclusive
    if (t == NB_SCAN - 1) row_ptr[N_NODES] = sm[t];  // = E
}

// scanC: row_ptr[i] = partials[b] + intra-block exclusive; cursor copy; dinv
__global__ __launch_bounds__(256) void k_scanC(const int* __restrict__ cnt,
                                               const int* __restrict__ partials,
                                               int* __restrict__ row_ptr,
                                               int* __restrict__ cursor,
                                               float* __restrict__ dinv) {
    __shared__ int sm[256];
    int t = threadIdx.x;
    int i = blockIdx.x * 256 + t;
    int v = (i < N_NODES) ? cnt[i] : 0;
    sm[t] = v;
    __syncthreads();
    for (int off = 1; off < 256; off <<= 1) {
        int add = (t >= off) ? sm[t - off] : 0;
        __syncthreads();
        sm[t] += add;
        __syncthreads();
    }
    if (i < N_NODES) {
        int p = partials[blockIdx.x] + sm[t] - v;  // exclusive prefix
        row_ptr[i] = p;
        cursor[i] = p;
        dinv[i] = rsqrtf(1.0f + (float)v);  // +1 self loop
    }
}

__global__ void k_scatter(const int* __restrict__ src, const int* __restrict__ dst,
                          int* __restrict__ cursor, int* __restrict__ csr_src) {
    int e = blockIdx.x * 256 + threadIdx.x;
    if (e < N_EDGES) {
        int pos = atomicAdd(&cursor[dst[e]], 1);
        csr_src[pos] = src[e];
    }
}

// ---------------------------------------------------------------------------
// GEMM1: h1s[N,128] = (x[N,165] @ W1[165,128]) * dinv[row]
// 32-row x-tile in LDS (stride 168). cp=t&63 -> cols {cp,cp+64}; rg=t>>6 -> 8 rows.
// #pragma unroll 2 prevents full-unroll register blowup (R1: VGPR=256, 1GB spills).
// ---------------------------------------------------------------------------
__global__ __launch_bounds__(256) void k_gemm1(const float* __restrict__ x,
                                               const float* __restrict__ W1,
                                               const float* __restrict__ dinv,
                                               float* __restrict__ h1s) {
    __shared__ float xs[32 * 168];
    const int row0 = blockIdx.x * 32;
    const int t = threadIdx.x;
    {
        const float* src = x + (size_t)row0 * F_IN;
        const int maxe = (N_NODES - row0) * F_IN;
        for (int fi = t; fi < 32 * F_IN; fi += 256) {
            int r = fi / F_IN;
            int k = fi - r * F_IN;
            xs[r * 168 + k] = (fi < maxe) ? src[fi] : 0.0f;
        }
        for (int r = t; r < 32; r += 256) {
            xs[r * 168 + 165] = 0.0f;
            xs[r * 168 + 166] = 0.0f;
            xs[r * 168 + 167] = 0.0f;
        }
    }
    __syncthreads();

    const int cp = t & 63;
    const int rg = t >> 6;

    float acc0[8], acc1[8];
#pragma unroll
    for (int r = 0; r < 8; r++) { acc0[r] = 0.0f; acc1[r] = 0.0f; }

#pragma unroll 2
    for (int k4 = 0; k4 < 164; k4 += 4) {
        float4 xv[8];
#pragma unroll
        for (int r = 0; r < 8; r++)
            xv[r] = *(const float4*)&xs[(rg * 8 + r) * 168 + k4];
        float w0[4], w1v[4];
#pragma unroll
        for (int j = 0; j < 4; j++) {
            w0[j]  = W1[(k4 + j) * F_HID + cp];
            w1v[j] = W1[(k4 + j) * F_HID + cp + 64];
        }
#pragma unroll
        for (int r = 0; r < 8; r++) {
            acc0[r] = fmaf(xv[r].x, w0[0], acc0[r]);
            acc0[r] = fmaf(xv[r].y, w0[1], acc0[r]);
            acc0[r] = fmaf(xv[r].z, w0[2], acc0[r]);
            acc0[r] = fmaf(xv[r].w, w0[3], acc0[r]);
            acc1[r] = fmaf(xv[r].x, w1v[0], acc1[r]);
            acc1[r] = fmaf(xv[r].y, w1v[1], acc1[r]);
            acc1[r] = fmaf(xv[r].z, w1v[2], acc1[r]);
            acc1[r] = fmaf(xv[r].w, w1v[3], acc1[r]);
        }
    }
    {   // remainder k = 164
        float w0  = W1[164 * F_HID + cp];
        float w1r = W1[164 * F_HID + cp + 64];
#pragma unroll
        for (int r = 0; r < 8; r++) {
            float xvr = xs[(rg * 8 + r) * 168 + 164];
            acc0[r] = fmaf(xvr, w0, acc0[r]);
            acc1[r] = fmaf(xvr, w1r, acc1[r]);
        }
    }
#pragma unroll
    for (int r = 0; r < 8; r++) {
        int row = row0 + rg * 8 + r;
        if (row < N_NODES) {
            float dv = dinv[row];
            h1s[(size_t)row * F_HID + cp]      = acc0[r] * dv;
            h1s[(size_t)row * F_HID + cp + 64] = acc1[r] * dv;
        }
    }
}

// ---------------------------------------------------------------------------
// CSR aggregation + fused BN stats:
// out[d,:] = dinv[d] * (hs[d,:] + sum_{s in in(d)} hs[s,:])
// TPN = C/4 threads per node (float4 each). Per-thread running sum/sumsq for
// its 4 columns, block-reduced, 2 atomics/col at the end.
// ---------------------------------------------------------------------------
template <int C, int TPN, int NPB>
__global__ __launch_bounds__(256) void k_aggr(const float* __restrict__ hs,
                                              const int* __restrict__ row_ptr,
                                              const int* __restrict__ csr_src,
                                              const float* __restrict__ dinv,
                                              float* __restrict__ out,
                                              float* __restrict__ gsum,
                                              float* __restrict__ gsumsq) {
    const int t = threadIdx.x;
    const int q = t & (TPN - 1);
    const int slot = t / TPN;
    float s0 = 0, s1 = 0, s2 = 0, s3 = 0;
    float q0 = 0, q1 = 0, q2 = 0, q3 = 0;

    for (int node = blockIdx.x * NPB + slot; node < N_NODES;
         node += gridDim.x * NPB) {
        int beg = row_ptr[node];
        int end = row_ptr[node + 1];
        float4 acc = *(const float4*)&hs[(size_t)node * C + q * 4];
        for (int e = beg; e < end; e++) {
            int s = csr_src[e];
            float4 v = *(const float4*)&hs[(size_t)s * C + q * 4];
            acc.x += v.x; acc.y += v.y; acc.z += v.z; acc.w += v.w;
        }
        float dv = dinv[node];
        acc.x *= dv; acc.y *= dv; acc.z *= dv; acc.w *= dv;
        *(float4*)&out[(size_t)node * C + q * 4] = acc;
        s0 += acc.x; s1 += acc.y; s2 += acc.z; s3 += acc.w;
        q0 = fmaf(acc.x, acc.x, q0); q1 = fmaf(acc.y, acc.y, q1);
        q2 = fmaf(acc.z, acc.z, q2); q3 = fmaf(acc.w, acc.w, q3);
    }

    __shared__ float sm[256 * 4];
    __shared__ float sq[256 * 4];
    sm[t * 4 + 0] = s0; sm[t * 4 + 1] = s1; sm[t * 4 + 2] = s2; sm[t * 4 + 3] = s3;
    sq[t * 4 + 0] = q0; sq[t * 4 + 1] = q1; sq[t * 4 + 2] = q2; sq[t * 4 + 3] = q3;
    __syncthreads();
    if (t < TPN) {
#pragma unroll
        for (int sl = 1; sl < NPB; sl++) {
            int u = (sl * TPN + t) * 4;
            s0 += sm[u + 0]; s1 += sm[u + 1]; s2 += sm[u + 2]; s3 += sm[u + 3];
            q0 += sq[u + 0]; q1 += sq[u + 1]; q2 += sq[u + 2]; q3 += sq[u + 3];
        }
        atomicAdd(&gsum[t * 4 + 0], s0); atomicAdd(&gsum[t * 4 + 1], s1);
        atomicAdd(&gsum[t * 4 + 2], s2); atomicAdd(&gsum[t * 4 + 3], s3);
        atomicAdd(&gsumsq[t * 4 + 0], q0); atomicAdd(&gsumsq[t * 4 + 1], q1);
        atomicAdd(&gsumsq[t * 4 + 2], q2); atomicAdd(&gsumsq[t * 4 + 3], q3);
    }
}

// scale = g*rstd ; shift = be - mean*scale
__global__ void k_bn_finalize(const float* gsum, const float* gsumsq,
                              const float* g, const float* be,
                              float* sc, float* sh, int C) {
    int c = threadIdx.x;
    if (c < C) {
        const float invn = 1.0f / (float)N_NODES;
        float mean = gsum[c] * invn;
        float var = gsumsq[c] * invn - mean * mean;
        float rstd = rsqrtf(var + BN_EPS);
        float scale = g[c] * rstd;
        sc[c] = scale;
        sh[c] = fmaf(-mean, scale, be[c]);
    }
}

// ---------------------------------------------------------------------------
// GEMM2 fused with BN1-apply + ReLU on load; epilogue scales by dinv:
// h2s[N,64] = (relu(bn1(out1[N,128])) @ W2[128,64]) * dinv[row]
// W2 staged in LDS (32 KB). 32-row tile; cp=t&31 -> cols {cp,cp+32}; rg=t>>5.
// #pragma unroll 2 prevents the R1 full-unroll spill (VGPR 256 -> ~64).
// ---------------------------------------------------------------------------
__global__ __launch_bounds__(256) void k_gemm2(const float* __restrict__ out1,
                                               const float* __restrict__ sc1,
                                               const float* __restrict__ sh1,
                                               const float* __restrict__ W2,
                                               const float* __restrict__ dinv,
                                               float* __restrict__ h2s) {
    __shared__ float xs[32 * 128];
    __shared__ float ws[128 * 64];
    const int row0 = blockIdx.x * 32;
    const int t = threadIdx.x;
    for (int i = t; i < 128 * 64; i += 256) ws[i] = W2[i];
    {
        const float* src = out1 + (size_t)row0 * F_HID;
        const int maxe = (N_NODES - row0) * F_HID;
        for (int fi = t; fi < 32 * F_HID; fi += 256) {
            int c = fi & 127;
            float v = (fi < maxe) ? src[fi] : 0.0f;
            v = fmaf(v, sc1[c], sh1[c]);
            xs[fi] = fmaxf(v, 0.0f);
        }
    }
    __syncthreads();

    const int cp = t & 31;
    const int rg = t >> 5;

    float acc0[4], acc1[4];
#pragma unroll
    for (int r = 0; r < 4; r++) { acc0[r] = 0.0f; acc1[r] = 0.0f; }

#pragma unroll 2
    for (int k4 = 0; k4 < F_HID; k4 += 4) {
        float4 xv[4];
#pragma unroll
        for (int r = 0; r < 4; r++)
            xv[r] = *(const float4*)&xs[(rg * 4 + r) * 128 + k4];
        float w0[4], w1v[4];
#pragma unroll
        for (int j = 0; j < 4; j++) {
            w0[j]  = ws[(k4 + j) * F_OUT + cp];
            w1v[j] = ws[(k4 + j) * F_OUT + cp + 32];
        }
#pragma unroll
        for (int r = 0; r < 4; r++) {
            acc0[r] = fmaf(xv[r].x, w0[0], acc0[r]);
            acc0[r] = fmaf(xv[r].y, w0[1], acc0[r]);
            acc0[r] = fmaf(xv[r].z, w0[2], acc0[r]);
            acc0[r] = fmaf(xv[r].w, w0[3], acc0[r]);
            acc1[r] = fmaf(xv[r].x, w1v[0], acc1[r]);
            acc1[r] = fmaf(xv[r].y, w1v[1], acc1[r]);
            acc1[r] = fmaf(xv[r].z, w1v[2], acc1[r]);
            acc1[r] = fmaf(xv[r].w, w1v[3], acc1[r]);
        }
    }
#pragma unroll
    for (int r = 0; r < 4; r++) {
        int row = row0 + rg * 4 + r;
        if (row < N_NODES) {
            float dv = dinv[row];
            h2s[(size_t)row * F_OUT + cp]      = acc0[r] * dv;
            h2s[(size_t)row * F_OUT + cp + 32] = acc1[r] * dv;
        }
    }
}

// ---------------------------------------------------------------------------
// Final: hf = bn2(out2[r,:]) -> d_out[r*64+c]; z = relu(hf@Wp1+bp1)@Wp2+bp2
// One wave per row; 64x64 dots via lane shuffles; Wp1/Wp2 in LDS.
// ---------------------------------------------------------------------------
__global__ __launch_bounds__(256) void k_final(const float* __restrict__ out2,
                                               const float* __restrict__ sc2,
                                               const float* __restrict__ sh2,
                                               const float* __restrict__ Wp1,
                                               const float* __restrict__ bp1,
                                               const float* __restrict__ Wp2,
                                               const float* __restrict__ bp2,
                                               float* __restrict__ out) {
    __shared__ float w1s[64 * 64];
    __shared__ float w2s[64 * 64];
    for (int i = threadIdx.x; i < 64 * 64; i += 256) {
        w1s[i] = Wp1[i];
        w2s[i] = Wp2[i];
    }
    __syncthreads();

    const int lane = threadIdx.x & 63;
    const int wid = threadIdx.x >> 6;
    const float scale = sc2[lane];
    const float shift = sh2[lane];
    const float b1v = bp1[lane];
    const float b2v = bp2[lane];
    const int nwaves = gridDim.x * 4;

    for (int row = blockIdx.x * 4 + wid; row < N_NODES; row += nwaves) {
        float hv = fmaf(out2[(size_t)row * 64 + lane], scale, shift);
        out[(size_t)row * 64 + lane] = hv;

        float acc = b1v;
#pragma unroll
        for (int k = 0; k < 64; k++) {
            float hk = __shfl(hv, k, 64);
            acc = fmaf(hk, w1s[k * 64 + lane], acc);
        }
        float a = fmaxf(acc, 0.0f);

        float acc2 = b2v;
#pragma unroll
        for (int k = 0; k < 64; k++) {
            float ak = __shfl(a, k, 64);
            acc2 = fmaf(ak, w2s[k * 64 + lane], acc2);
        }
        out[(size_t)(N_NODES) * 64 + (size_t)row * 64 + lane] = acc2;
    }
}

// ---------------------------------------------------------------------------
// launch
// ---------------------------------------------------------------------------
extern "C" void kernel_launch(void* const* d_in, const int* in_sizes, int n_in,
                              void* d_out, int out_size, void* d_ws, size_t ws_size,
                              hipStream_t stream) {
    const float* x   = (const float*)d_in[0];
    const int*   ei  = (const int*)d_in[1];
    const float* W1  = (const float*)d_in[2];
    // b1 (d_in[3]) skipped: column-constant shift cancelled by BN1
    const float* g1  = (const float*)d_in[4];
    const float* be1 = (const float*)d_in[5];
    const float* W2  = (const float*)d_in[6];
    // b2 (d_in[7]) skipped: cancelled by BN2
    const float* g2  = (const float*)d_in[8];
    const float* be2 = (const float*)d_in[9];
    const float* Wp1 = (const float*)d_in[10];
    const float* bp1 = (const float*)d_in[11];
    const float* Wp2 = (const float*)d_in[12];
    const float* bp2 = (const float*)d_in[13];

    const int* src = ei;            // edge_index[0]
    const int* dst = ei + N_EDGES;  // edge_index[1]

    float* ws = (float*)d_ws;
    float* A    = ws;                          // h1s (N*128) / h2s (N*64)
    float* B    = A + (size_t)N_NODES * 128;   // out1 (N*128) / out2 (N*64)
    float* dinv = B + (size_t)N_NODES * 128;   // N
    float* st   = dinv + N_NODES;              // 768 floats of stats
    float* s1   = st;        float* s1q  = st + 128;
    float* sc1  = st + 256;  float* sh1  = st + 384;
    float* s2   = st + 512;  float* s2q  = st + 576;
    float* sc2  = st + 640;  float* sh2  = st + 704;
    int* cnt      = (int*)(st + 768);          // N  (memset with stats: contiguous)
    int* row_ptr  = cnt + N_NODES;             // N+1
    int* cursor   = row_ptr + N_NODES + 1;     // N
    int* csr_src  = cursor + N_NODES;          // E
    int* partials = csr_src + N_EDGES;         // NB_SCAN

    // zero stats + cnt in one shot (contiguous)
    hipMemsetAsync(st, 0, (768 + N_NODES) * sizeof(float), stream);

    const int EB = (N_EDGES + 255) / 256;

    // CSR build + dinv
    k_count<<<EB, 256, 0, stream>>>(dst, cnt);
    k_scanA<<<NB_SCAN, 256, 0, stream>>>(cnt, partials);
    k_scanB<<<1, 1024, 0, stream>>>(partials, row_ptr);
    k_scanC<<<NB_SCAN, 256, 0, stream>>>(cnt, partials, row_ptr, cursor, dinv);
    k_scatter<<<EB, 256, 0, stream>>>(src, dst, cursor, csr_src);

    // layer 1
    k_gemm1<<<(N_NODES + 31) / 32, 256, 0, stream>>>(x, W1, dinv, A);
    k_aggr<128, 32, 8><<<1024, 256, 0, stream>>>(A, row_ptr, csr_src, dinv, B, s1, s1q);
    k_bn_finalize<<<1, 128, 0, stream>>>(s1, s1q, g1, be1, sc1, sh1, 128);

    // layer 2 (BN1+relu fused into GEMM2 load)
    k_gemm2<<<(N_NODES + 31) / 32, 256, 0, stream>>>(B, sc1, sh1, W2, dinv, A);
    k_aggr<64, 16, 16><<<1024, 256, 0, stream>>>(A, row_ptr, csr_src, dinv, B, s2, s2q);
    k_bn_finalize<<<1, 64, 0, stream>>>(s2, s2q, g2, be2, sc2, sh2, 64);

    // BN2-apply + MLP head, writes both outputs
    k_final<<<2048, 256, 0, stream>>>(B, sc2, sh2, Wp1, bp1, Wp2, bp2, (float*)d_out);
}

// Round 3
// 980.867 us; speedup vs baseline: 2.5980x; 1.1486x over previous
//
#include <hip/hip_runtime.h>
#include <hip/hip_bf16.h>

#define N_NODES 203769
#define N_EDGES 234355
#define F_IN    165
#define F_HID   128
#define F_OUT   64
#define BN_EPS  1e-5f
#define NB_SCAN 796   // ceil(N_NODES/256)

// ---------------------------------------------------------------------------
// CSR build: count in-degree (int atomics)
// ---------------------------------------------------------------------------
__global__ void k_count(const int* __restrict__ dst, int* __restrict__ cnt) {
    int e = blockIdx.x * 256 + threadIdx.x;
    if (e < N_EDGES) atomicAdd(&cnt[dst[e]], 1);
}

__global__ __launch_bounds__(256) void k_scanA(const int* __restrict__ cnt,
                                               int* __restrict__ partials) {
    __shared__ int sm[256];
    int t = threadIdx.x;
    int i = blockIdx.x * 256 + t;
    int v = (i < N_NODES) ? cnt[i] : 0;
    sm[t] = v;
    __syncthreads();
    for (int off = 128; off > 0; off >>= 1) {
        if (t < off) sm[t] += sm[t + off];
        __syncthreads();
    }
    if (t == 0) partials[blockIdx.x] = sm[0];
}

__global__ __launch_bounds__(1024) void k_scanB(int* __restrict__ partials,
                                                int* __restrict__ row_ptr) {
    __shared__ int sm[1024];
    int t = threadIdx.x;
    int v = (t < NB_SCAN) ? partials[t] : 0;
    sm[t] = v;
    __syncthreads();
    for (int off = 1; off < 1024; off <<= 1) {
        int add = (t >= off) ? sm[t - off] : 0;
        __syncthreads();
        sm[t] += add;
        __syncthreads();
    }
    if (t < NB_SCAN) partials[t] = sm[t] - v;   // exclusive
    if (t == NB_SCAN - 1) row_ptr[N_NODES] = sm[t];  // = E
}

__global__ __launch_bounds__(256) void k_scanC(const int* __restrict__ cnt,
                                               const int* __restrict__ partials,
                                               int* __restrict__ row_ptr,
                                               int* __restrict__ cursor,
                                               float* __restrict__ dinv) {
    __shared__ int sm[256];
    int t = threadIdx.x;
    int i = blockIdx.x * 256 + t;
    int v = (i < N_NODES) ? cnt[i] : 0;
    sm[t] = v;
    __syncthreads();
    for (int off = 1; off < 256; off <<= 1) {
        int add = (t >= off) ? sm[t - off] : 0;
        __syncthreads();
        sm[t] += add;
        __syncthreads();
    }
    if (i < N_NODES) {
        int p = partials[blockIdx.x] + sm[t] - v;  // exclusive prefix
        row_ptr[i] = p;
        cursor[i] = p;
        dinv[i] = rsqrtf(1.0f + (float)v);  // +1 self loop
    }
}

__global__ void k_scatter(const int* __restrict__ src, const int* __restrict__ dst,
                          int* __restrict__ cursor, int* __restrict__ csr_src) {
    int e = blockIdx.x * 256 + threadIdx.x;
    if (e < N_EDGES) {
        int pos = atomicAdd(&cursor[dst[e]], 1);
        csr_src[pos] = src[e];
    }
}

// ---------------------------------------------------------------------------
// GEMM1: h1s[N,128] = (x[N,165] @ W1[165,128]) * dinv[row]
// 64-row tile in LDS (stride 168 -> per-instr rows land on disjoint banks).
// Thread = 4 rows x 8 cols (c0=(t&15)*8, r0=(t>>4)*4). x via ds_read_b128,
// W1 via global float4 (16-lane broadcast, L1-resident). DS pipe: 4 b128 per
// 128 MACs -> VALU-bound (R2 was DS-bound at 8 b128 + 8 b32 per 64 MACs).
// ---------------------------------------------------------------------------
__global__ __launch_bounds__(256) void k_gemm1(const float* __restrict__ x,
                                               const float* __restrict__ W1,
                                               const float* __restrict__ dinv,
                                               float* __restrict__ h1s) {
    __shared__ float xs[64 * 168];  // 43 KB
    const int row0 = blockIdx.x * 64;
    const int t = threadIdx.x;
    {
        const float* src = x + (size_t)row0 * F_IN;
        const int maxe = (N_NODES - row0) * F_IN;
        for (int fi = t; fi < 64 * F_IN; fi += 256) {
            int r = fi / F_IN;
            int k = fi - r * F_IN;
            xs[r * 168 + k] = (fi < maxe) ? src[fi] : 0.0f;
        }
        if (t < 64) {
            xs[t * 168 + 165] = 0.0f;
            xs[t * 168 + 166] = 0.0f;
            xs[t * 168 + 167] = 0.0f;
        }
    }
    __syncthreads();

    const int c0 = (t & 15) * 8;
    const int r0 = (t >> 4) * 4;

    float acc[4][8];
#pragma unroll
    for (int r = 0; r < 4; r++)
#pragma unroll
        for (int c = 0; c < 8; c++) acc[r][c] = 0.0f;

#pragma unroll 2
    for (int k4 = 0; k4 < 164; k4 += 4) {
        float4 xv[4];
#pragma unroll
        for (int r = 0; r < 4; r++)
            xv[r] = *(const float4*)&xs[(r0 + r) * 168 + k4];
        float4 wa[4], wb[4];
#pragma unroll
        for (int j = 0; j < 4; j++) {
            wa[j] = *(const float4*)&W1[(k4 + j) * F_HID + c0];
            wb[j] = *(const float4*)&W1[(k4 + j) * F_HID + c0 + 4];
        }
#pragma unroll
        for (int r = 0; r < 4; r++) {
            const float xr[4] = {xv[r].x, xv[r].y, xv[r].z, xv[r].w};
#pragma unroll
            for (int j = 0; j < 4; j++) {
                acc[r][0] = fmaf(xr[j], wa[j].x, acc[r][0]);
                acc[r][1] = fmaf(xr[j], wa[j].y, acc[r][1]);
                acc[r][2] = fmaf(xr[j], wa[j].z, acc[r][2]);
                acc[r][3] = fmaf(xr[j], wa[j].w, acc[r][3]);
                acc[r][4] = fmaf(xr[j], wb[j].x, acc[r][4]);
                acc[r][5] = fmaf(xr[j], wb[j].y, acc[r][5]);
                acc[r][6] = fmaf(xr[j], wb[j].z, acc[r][6]);
                acc[r][7] = fmaf(xr[j], wb[j].w, acc[r][7]);
            }
        }
    }
    {   // remainder k = 164
        float4 wa = *(const float4*)&W1[164 * F_HID + c0];
        float4 wb = *(const float4*)&W1[164 * F_HID + c0 + 4];
#pragma unroll
        for (int r = 0; r < 4; r++) {
            float xr = xs[(r0 + r) * 168 + 164];
            acc[r][0] = fmaf(xr, wa.x, acc[r][0]);
            acc[r][1] = fmaf(xr, wa.y, acc[r][1]);
            acc[r][2] = fmaf(xr, wa.z, acc[r][2]);
            acc[r][3] = fmaf(xr, wa.w, acc[r][3]);
            acc[r][4] = fmaf(xr, wb.x, acc[r][4]);
            acc[r][5] = fmaf(xr, wb.y, acc[r][5]);
            acc[r][6] = fmaf(xr, wb.z, acc[r][6]);
            acc[r][7] = fmaf(xr, wb.w, acc[r][7]);
        }
    }
#pragma unroll
    for (int r = 0; r < 4; r++) {
        int row = row0 + r0 + r;
        if (row < N_NODES) {
            float dv = dinv[row];
            float4 o0 = {acc[r][0] * dv, acc[r][1] * dv, acc[r][2] * dv, acc[r][3] * dv};
            float4 o1 = {acc[r][4] * dv, acc[r][5] * dv, acc[r][6] * dv, acc[r][7] * dv};
            *(float4*)&h1s[(size_t)row * F_HID + c0]     = o0;
            *(float4*)&h1s[(size_t)row * F_HID + c0 + 4] = o1;
        }
    }
}

// ---------------------------------------------------------------------------
// CSR aggregation + fused BN stats (unchanged from R2):
// out[d,:] = dinv[d] * (hs[d,:] + sum_{s in in(d)} hs[s,:])
// ---------------------------------------------------------------------------
template <int C, int TPN, int NPB>
__global__ __launch_bounds__(256) void k_aggr(const float* __restrict__ hs,
                                              const int* __restrict__ row_ptr,
                                              const int* __restrict__ csr_src,
                                              const float* __restrict__ dinv,
                                              float* __restrict__ out,
                                              float* __restrict__ gsum,
                                              float* __restrict__ gsumsq) {
    const int t = threadIdx.x;
    const int q = t & (TPN - 1);
    const int slot = t / TPN;
    float s0 = 0, s1 = 0, s2 = 0, s3 = 0;
    float q0 = 0, q1 = 0, q2 = 0, q3 = 0;

    for (int node = blockIdx.x * NPB + slot; node < N_NODES;
         node += gridDim.x * NPB) {
        int beg = row_ptr[node];
        int end = row_ptr[node + 1];
        float4 acc = *(const float4*)&hs[(size_t)node * C + q * 4];
        for (int e = beg; e < end; e++) {
            int s = csr_src[e];
            float4 v = *(const float4*)&hs[(size_t)s * C + q * 4];
            acc.x += v.x; acc.y += v.y; acc.z += v.z; acc.w += v.w;
        }
        float dv = dinv[node];
        acc.x *= dv; acc.y *= dv; acc.z *= dv; acc.w *= dv;
        *(float4*)&out[(size_t)node * C + q * 4] = acc;
        s0 += acc.x; s1 += acc.y; s2 += acc.z; s3 += acc.w;
        q0 = fmaf(acc.x, acc.x, q0); q1 = fmaf(acc.y, acc.y, q1);
        q2 = fmaf(acc.z, acc.z, q2); q3 = fmaf(acc.w, acc.w, q3);
    }

    __shared__ float sm[256 * 4];
    __shared__ float sq[256 * 4];
    sm[t * 4 + 0] = s0; sm[t * 4 + 1] = s1; sm[t * 4 + 2] = s2; sm[t * 4 + 3] = s3;
    sq[t * 4 + 0] = q0; sq[t * 4 + 1] = q1; sq[t * 4 + 2] = q2; sq[t * 4 + 3] = q3;
    __syncthreads();
    if (t < TPN) {
#pragma unroll
        for (int sl = 1; sl < NPB; sl++) {
            int u = (sl * TPN + t) * 4;
            s0 += sm[u + 0]; s1 += sm[u + 1]; s2 += sm[u + 2]; s3 += sm[u + 3];
            q0 += sq[u + 0]; q1 += sq[u + 1]; q2 += sq[u + 2]; q3 += sq[u + 3];
        }
        atomicAdd(&gsum[t * 4 + 0], s0); atomicAdd(&gsum[t * 4 + 1], s1);
        atomicAdd(&gsum[t * 4 + 2], s2); atomicAdd(&gsum[t * 4 + 3], s3);
        atomicAdd(&gsumsq[t * 4 + 0], q0); atomicAdd(&gsumsq[t * 4 + 1], q1);
        atomicAdd(&gsumsq[t * 4 + 2], q2); atomicAdd(&gsumsq[t * 4 + 3], q3);
    }
}

// scale = g*rstd ; shift = be - mean*scale
__global__ void k_bn_finalize(const float* gsum, const float* gsumsq,
                              const float* g, const float* be,
                              float* sc, float* sh, int C) {
    int c = threadIdx.x;
    if (c < C) {
        const float invn = 1.0f / (float)N_NODES;
        float mean = gsum[c] * invn;
        float var = gsumsq[c] * invn - mean * mean;
        float rstd = rsqrtf(var + BN_EPS);
        float scale = g[c] * rstd;
        sc[c] = scale;
        sh[c] = fmaf(-mean, scale, be[c]);
    }
}

// ---------------------------------------------------------------------------
// GEMM2 fused with BN1-apply + ReLU on load; epilogue scales by dinv:
// h2s[N,64] = (relu(bn1(out1[N,128])) @ W2[128,64]) * dinv[row]
// 64-row tile (stride 132, bank-clean), thread = 4r x 4c, W2 from global.
// ---------------------------------------------------------------------------
__global__ __launch_bounds__(256) void k_gemm2(const float* __restrict__ out1,
                                               const float* __restrict__ sc1,
                                               const float* __restrict__ sh1,
                                               const float* __restrict__ W2,
                                               const float* __restrict__ dinv,
                                               float* __restrict__ h2s) {
    __shared__ float xs[64 * 132];  // 33.8 KB
    const int row0 = blockIdx.x * 64;
    const int t = threadIdx.x;
    {
        const float* src = out1 + (size_t)row0 * F_HID;
        const int maxe = (N_NODES - row0) * F_HID;
        for (int fi = t; fi < 64 * F_HID; fi += 256) {
            int r = fi >> 7;
            int c = fi & 127;
            float v = (fi < maxe) ? src[fi] : 0.0f;
            v = fmaf(v, sc1[c], sh1[c]);
            xs[r * 132 + c] = fmaxf(v, 0.0f);
        }
    }
    __syncthreads();

    const int c0 = (t & 15) * 4;
    const int r0 = (t >> 4) * 4;

    float acc[4][4];
#pragma unroll
    for (int r = 0; r < 4; r++)
#pragma unroll
        for (int c = 0; c < 4; c++) acc[r][c] = 0.0f;

#pragma unroll 2
    for (int k4 = 0; k4 < F_HID; k4 += 4) {
        float4 xv[4];
#pragma unroll
        for (int r = 0; r < 4; r++)
            xv[r] = *(const float4*)&xs[(r0 + r) * 132 + k4];
        float4 w[4];
#pragma unroll
        for (int j = 0; j < 4; j++)
            w[j] = *(const float4*)&W2[(k4 + j) * F_OUT + c0];
#pragma unroll
        for (int r = 0; r < 4; r++) {
            const float xr[4] = {xv[r].x, xv[r].y, xv[r].z, xv[r].w};
#pragma unroll
            for (int j = 0; j < 4; j++) {
                acc[r][0] = fmaf(xr[j], w[j].x, acc[r][0]);
                acc[r][1] = fmaf(xr[j], w[j].y, acc[r][1]);
                acc[r][2] = fmaf(xr[j], w[j].z, acc[r][2]);
                acc[r][3] = fmaf(xr[j], w[j].w, acc[r][3]);
            }
        }
    }
#pragma unroll
    for (int r = 0; r < 4; r++) {
        int row = row0 + r0 + r;
        if (row < N_NODES) {
            float dv = dinv[row];
            float4 o = {acc[r][0] * dv, acc[r][1] * dv, acc[r][2] * dv, acc[r][3] * dv};
            *(float4*)&h2s[(size_t)row * F_OUT + c0] = o;
        }
    }
}

// ---------------------------------------------------------------------------
// Final: hf = bn2(out2) -> d_out[0:N*64]; z = relu(hf@Wp1+bp1)@Wp2+bp2 -> rest
// 64-row tile; two LDS GEMMs (K=64), thread = 4r x 4c, weights from global
// (L1-resident, 16-lane broadcast). Replaces R2's shuffle version (DS-bound:
// 128 ds_bpermute per row).
// ---------------------------------------------------------------------------
__global__ __launch_bounds__(256) void k_final(const float* __restrict__ out2,
                                               const float* __restrict__ sc2,
                                               const float* __restrict__ sh2,
                                               const float* __restrict__ Wp1,
                                               const float* __restrict__ bp1,
                                               const float* __restrict__ Wp2,
                                               const float* __restrict__ bp2,
                                               float* __restrict__ out) {
    __shared__ float hs[64 * 68];   // 17.4 KB
    __shared__ float as_[64 * 68];  // 17.4 KB
    const int row0 = blockIdx.x * 64;
    const int t = threadIdx.x;

    // stage: BN2-apply, write h output, keep in LDS
    {
        const float4* src = (const float4*)out2;
        float4* dsth = (float4*)out;
#pragma unroll
        for (int i = 0; i < 4; i++) {
            int f4 = t + i * 256;         // 0..1023
            int r = f4 >> 4;
            int c4 = f4 & 15;
            int grow = row0 + r;
            float4 v = {0, 0, 0, 0};
            if (grow < N_NODES) v = src[(size_t)grow * 16 + c4];
            int c = c4 * 4;
            v.x = fmaf(v.x, sc2[c + 0], sh2[c + 0]);
            v.y = fmaf(v.y, sc2[c + 1], sh2[c + 1]);
            v.z = fmaf(v.z, sc2[c + 2], sh2[c + 2]);
            v.w = fmaf(v.w, sc2[c + 3], sh2[c + 3]);
            if (grow < N_NODES) dsth[(size_t)grow * 16 + c4] = v;
            *(float4*)&hs[r * 68 + c] = v;
        }
    }
    __syncthreads();

    const int c0 = (t & 15) * 4;
    const int r0 = (t >> 4) * 4;

    // GEMM A: a = relu(hs @ Wp1 + bp1)
    {
        float acc[4][4];
#pragma unroll
        for (int r = 0; r < 4; r++)
#pragma unroll
            for (int c = 0; c < 4; c++) acc[r][c] = 0.0f;
#pragma unroll 2
        for (int k4 = 0; k4 < 64; k4 += 4) {
            float4 xv[4];
#pragma unroll
            for (int r = 0; r < 4; r++)
                xv[r] = *(const float4*)&hs[(r0 + r) * 68 + k4];
            float4 w[4];
#pragma unroll
            for (int j = 0; j < 4; j++)
                w[j] = *(const float4*)&Wp1[(k4 + j) * 64 + c0];
#pragma unroll
            for (int r = 0; r < 4; r++) {
                const float xr[4] = {xv[r].x, xv[r].y, xv[r].z, xv[r].w};
#pragma unroll
                for (int j = 0; j < 4; j++) {
                    acc[r][0] = fmaf(xr[j], w[j].x, acc[r][0]);
                    acc[r][1] = fmaf(xr[j], w[j].y, acc[r][1]);
                    acc[r][2] = fmaf(xr[j], w[j].z, acc[r][2]);
                    acc[r][3] = fmaf(xr[j], w[j].w, acc[r][3]);
                }
            }
        }
        float4 b = *(const float4*)&bp1[c0];
#pragma unroll
        for (int r = 0; r < 4; r++) {
            float4 o = {fmaxf(acc[r][0] + b.x, 0.0f), fmaxf(acc[r][1] + b.y, 0.0f),
                        fmaxf(acc[r][2] + b.z, 0.0f), fmaxf(acc[r][3] + b.w, 0.0f)};
            *(float4*)&as_[(r0 + r) * 68 + c0] = o;
        }
    }
    __syncthreads();

    // GEMM B: z = a @ Wp2 + bp2
    {
        float acc[4][4];
#pragma unroll
        for (int r = 0; r < 4; r++)
#pragma unroll
            for (int c = 0; c < 4; c++) acc[r][c] = 0.0f;
#pragma unroll 2
        for (int k4 = 0; k4 < 64; k4 += 4) {
            float4 xv[4];
#pragma unroll
            for (int r = 0; r < 4; r++)
                xv[r] = *(const float4*)&as_[(r0 + r) * 68 + k4];
            float4 w[4];
#pragma unroll
            for (int j = 0; j < 4; j++)
                w[j] = *(const float4*)&Wp2[(k4 + j) * 64 + c0];
#pragma unroll
            for (int r = 0; r < 4; r++) {
                const float xr[4] = {xv[r].x, xv[r].y, xv[r].z, xv[r].w};
#pragma unroll
                for (int j = 0; j < 4; j++) {
                    acc[r][0] = fmaf(xr[j], w[j].x, acc[r][0]);
                    acc[r][1] = fmaf(xr[j], w[j].y, acc[r][1]);
                    acc[r][2] = fmaf(xr[j], w[j].z, acc[r][2]);
                    acc[r][3] = fmaf(xr[j], w[j].w, acc[r][3]);
                }
            }
        }
        float4 b = *(const float4*)&bp2[c0];
        float* zout = out + (size_t)N_NODES * 64;
#pragma unroll
        for (int r = 0; r < 4; r++) {
            int row = row0 + r0 + r;
            if (row < N_NODES) {
                float4 o = {acc[r][0] + b.x, acc[r][1] + b.y,
                            acc[r][2] + b.z, acc[r][3] + b.w};
                *(float4*)&zout[(size_t)row * 64 + c0] = o;
            }
        }
    }
}

// ---------------------------------------------------------------------------
// launch
// ---------------------------------------------------------------------------
extern "C" void kernel_launch(void* const* d_in, const int* in_sizes, int n_in,
                              void* d_out, int out_size, void* d_ws, size_t ws_size,
                              hipStream_t stream) {
    const float* x   = (const float*)d_in[0];
    const int*   ei  = (const int*)d_in[1];
    const float* W1  = (const float*)d_in[2];
    // b1 (d_in[3]) skipped: column-constant shift cancelled by BN1
    const float* g1  = (const float*)d_in[4];
    const float* be1 = (const float*)d_in[5];
    const float* W2  = (const float*)d_in[6];
    // b2 (d_in[7]) skipped: cancelled by BN2
    const float* g2  = (const float*)d_in[8];
    const float* be2 = (const float*)d_in[9];
    const float* Wp1 = (const float*)d_in[10];
    const float* bp1 = (const float*)d_in[11];
    const float* Wp2 = (const float*)d_in[12];
    const float* bp2 = (const float*)d_in[13];

    const int* src = ei;            // edge_index[0]
    const int* dst = ei + N_EDGES;  // edge_index[1]

    float* ws = (float*)d_ws;
    float* A    = ws;                          // h1s (N*128) / h2s (N*64)
    float* B    = A + (size_t)N_NODES * 128;   // out1 (N*128) / out2 (N*64)
    float* dinv = B + (size_t)N_NODES * 128;   // N
    float* st   = dinv + N_NODES;              // 768 floats of stats
    float* s1   = st;        float* s1q  = st + 128;
    float* sc1  = st + 256;  float* sh1  = st + 384;
    float* s2   = st + 512;  float* s2q  = st + 576;
    float* sc2  = st + 640;  float* sh2  = st + 704;
    int* cnt      = (int*)(st + 768);          // N
    int* row_ptr  = cnt + N_NODES;             // N+1
    int* cursor   = row_ptr + N_NODES + 1;     // N
    int* csr_src  = cursor + N_NODES;          // E
    int* partials = csr_src + N_EDGES;         // NB_SCAN

    hipMemsetAsync(st, 0, (768 + N_NODES) * sizeof(float), stream);

    const int EB = (N_EDGES + 255) / 256;
    const int GB = (N_NODES + 63) / 64;

    // CSR build + dinv
    k_count<<<EB, 256, 0, stream>>>(dst, cnt);
    k_scanA<<<NB_SCAN, 256, 0, stream>>>(cnt, partials);
    k_scanB<<<1, 1024, 0, stream>>>(partials, row_ptr);
    k_scanC<<<NB_SCAN, 256, 0, stream>>>(cnt, partials, row_ptr, cursor, dinv);
    k_scatter<<<EB, 256, 0, stream>>>(src, dst, cursor, csr_src);

    // layer 1
    k_gemm1<<<GB, 256, 0, stream>>>(x, W1, dinv, A);
    k_aggr<128, 32, 8><<<1024, 256, 0, stream>>>(A, row_ptr, csr_src, dinv, B, s1, s1q);
    k_bn_finalize<<<1, 128, 0, stream>>>(s1, s1q, g1, be1, sc1, sh1, 128);

    // layer 2 (BN1+relu fused into GEMM2 load)
    k_gemm2<<<GB, 256, 0, stream>>>(B, sc1, sh1, W2, dinv, A);
    k_aggr<64, 16, 16><<<1024, 256, 0, stream>>>(A, row_ptr, csr_src, dinv, B, s2, s2q);
    k_bn_finalize<<<1, 64, 0, stream>>>(s2, s2q, g2, be2, sc2, sh2, 64);

    // BN2-apply + MLP head, writes both outputs
    k_final<<<GB, 256, 0, stream>>>(B, sc2, sh2, Wp1, bp1, Wp2, bp2, (float*)d_out);
}